// Round 7
// baseline (107.676 us; speedup 1.0000x reference)
//
#include <hip/hip_runtime.h>
#include <hip/hip_bf16.h>

#define NR 8192
#define KF 512
#define OF 256

// ws float offsets
#define WS_AL   0        // alpha [8192]
#define WS_BE   8192     // beta  [8192]
#define WS_GA   16384    // gamma [8192]
#define WS_PP   24576    // r_p partials [256][512]
#define WS_PQ   155648   // r_q partials [256][512]
#define WS_UP   286720   // U partials [16][256]
#define WS_VP   290816   // V partials [16][256]
#define WS_FLAG 294912   // uint flag (index in uint units)
#define BT_BYTE_OFF 1179904   // bf16 Bt[256][512] = 256 KB

typedef float f32x4 __attribute__((ext_vector_type(4)));
typedef __bf16 bf16x8 __attribute__((ext_vector_type(8)));

// ---------------------------------------------------------------------------
// kA: 256 blocks x 512 thr, 32 rows each.
//  - block 0: reset flag to 0
//  - Bt row blk: Bt[blk][m] = bf16(weight[m][blk])  (one-time transpose, spread)
//  - local Sa/Sb, per-row alpha/beta/gamma -> ws, p/q -> LDS
//  - column-reduction partials: pP[blk][m] = sum_{rows} p_j * input[j][m]
// ---------------------------------------------------------------------------
__global__ __launch_bounds__(512) void kA(const float* __restrict__ input,
                                          const float* __restrict__ w_s,
                                          const float* __restrict__ w_r,
                                          const float* __restrict__ weight,
                                          float* __restrict__ ws,
                                          __hip_bfloat16* __restrict__ BtH) {
    __shared__ f32x4 red[512];
    __shared__ float pl[32], ql[32];
    __shared__ float wred[16];
    const int tid  = threadIdx.x;
    const int blk  = blockIdx.x;
    const int base = blk * 32;

    if (blk == 0 && tid == 0) ((unsigned*)ws)[WS_FLAG] = 0u;

    // Bt[blk][tid] = bf16(weight[tid][blk]); coalesced 2B stores per wave
    {
        __bf16* Bt = (__bf16*)BtH;
        Bt[blk * KF + tid] = (__bf16)weight[tid * OF + blk];
    }

    // ---- Sa/Sb: full local reduction (vectorized, L2-hot) ----
    float la = 0.f, lb = 0.f;
#pragma unroll
    for (int i = 0; i < 4; ++i) {
        const int off = i * 2048 + tid * 4;
        const f32x4 va = *(const f32x4*)(w_s + off);
        const f32x4 vb = *(const f32x4*)(w_r + off);
        la += fabsf(va[0]) + fabsf(va[1]) + fabsf(va[2]) + fabsf(va[3]);
        lb += fabsf(vb[0]) + fabsf(vb[1]) + fabsf(vb[2]) + fabsf(vb[3]);
    }
#pragma unroll
    for (int o = 32; o > 0; o >>= 1) {
        la += __shfl_down(la, o);
        lb += __shfl_down(lb, o);
    }
    if ((tid & 63) == 0) { wred[tid >> 6] = la; wred[8 + (tid >> 6)] = lb; }
    __syncthreads();

    // ---- per-row scalars ----
    if (tid < 32) {
        float Sa = 0.f, Sb = 0.f;
#pragma unroll
        for (int i = 0; i < 8; ++i) { Sa += wred[i]; Sb += wred[8 + i]; }
        const int row = base + tid;
        const float a = fabsf(w_s[row]);
        const float b = fabsf(w_r[row]);
        float s = 0.5f * (a * (Sb - b) + b * (Sa - a));
        if (s == 0.f) s = 1.f;
        const float d = 1.0f / sqrtf(s);
        ws[WS_AL + row] = 0.5f * d * a;
        ws[WS_BE + row] = 0.5f * d * b;
        ws[WS_GA + row] = d * d * a * b;
        pl[tid] = d * b;
        ql[tid] = d * a;
    }
    __syncthreads();

    // ---- column-reduction partials over this block's 32 rows ----
    const int c4 = (tid & 127) * 4;
    const int rg = tid >> 7;            // 0..3 -> row octets
    f32x4 accp = {0.f,0.f,0.f,0.f}, accq = {0.f,0.f,0.f,0.f};
#pragma unroll
    for (int r = 0; r < 8; ++r) {
        const int jl = rg * 8 + r;
        const f32x4 v = *(const f32x4*)(input + (base + jl) * KF + c4);
        accp += pl[jl] * v;
        accq += ql[jl] * v;
    }
    red[tid] = accp;
    __syncthreads();
    if (tid < 128) {
        const f32x4 s = red[tid] + red[tid + 128] + red[tid + 256] + red[tid + 384];
        *(f32x4*)(ws + WS_PP + blk * KF + c4) = s;
    }
    __syncthreads();
    red[tid] = accq;
    __syncthreads();
    if (tid < 128) {
        const f32x4 s = red[tid] + red[tid + 128] + red[tid + 256] + red[tid + 384];
        *(f32x4*)(ws + WS_PQ + blk * KF + c4) = s;
    }
}

// ---------------------------------------------------------------------------
// kC: 256 blocks x 512 thr, 32 rows each.
//  - blocks 0..15: reduce partial slice -> r_p/r_q[32], U/V partial -> ws,
//    threadfence + atomicAdd(flag)
//  - all blocks: H tile (32x256) via MFMA (B from global Bt), H -> LDS
//  - epilogue: spin flag>=16, UL/VL = sum of 16 partials,
//    out = alpha*U + beta*V - gamma*H (coalesced f32x4)
// ---------------------------------------------------------------------------
__global__ __launch_bounds__(512) void kC(const float* __restrict__ input,
                                          const __hip_bfloat16* __restrict__ BtH,
                                          const float* __restrict__ weight,
                                          float* __restrict__ ws,
                                          float* __restrict__ out) {
    __shared__ float H[32 * 257];          // 32.9 KB
    __shared__ float aL[32], bL[32], gL[32];
    __shared__ float UL[256], VL[256];
    __shared__ float r_pl[32], r_ql[32];
    __shared__ float redp[16][32], redq[16][32];
    __shared__ float uh[2][256], vh[2][256];

    const int tid  = threadIdx.x;
    const int blk  = blockIdx.x;
    const int base = blk * 32;
    const __bf16* Bt = (const __bf16*)BtH;
    unsigned* flag = (unsigned*)ws + WS_FLAG;

    // ================= producer blocks: U/V partials =================
    if (blk < 16) {
        const int mloc = tid & 31;
        const int m    = blk * 32 + mloc;
        const int bg   = tid >> 5;         // 0..15
        float sp = 0.f, sq = 0.f;
        for (int b = bg; b < 256; b += 16) {
            sp += ws[WS_PP + b * KF + m];
            sq += ws[WS_PQ + b * KF + m];
        }
        redp[bg][mloc] = sp; redq[bg][mloc] = sq;
        __syncthreads();
        if (tid < 32) {
            float tp = 0.f, tq = 0.f;
#pragma unroll
            for (int g = 0; g < 16; ++g) { tp += redp[g][tid]; tq += redq[g][tid]; }
            r_pl[tid] = tp; r_ql[tid] = tq;
        }
        __syncthreads();
        const int k  = tid & 255;
        const int hf = tid >> 8;
        float u = 0.f, v = 0.f;
#pragma unroll
        for (int mm = 0; mm < 16; ++mm) {
            const int ml = hf * 16 + mm;
            const float wv = weight[(blk * 32 + ml) * OF + k];
            u += r_pl[ml] * wv;
            v += r_ql[ml] * wv;
        }
        uh[hf][k] = u; vh[hf][k] = v;
        __syncthreads();
        if (tid < 256) ws[WS_UP + blk * 256 + tid] = uh[0][tid] + uh[1][tid];
        else {
            const int k2 = tid - 256;
            ws[WS_VP + blk * 256 + k2] = vh[0][k2] + vh[1][k2];
        }
        __threadfence();
        __syncthreads();
        if (tid == 0) atomicAdd(flag, 1u);
    }

    // ================= MFMA H-tile (all blocks) =================
    {
        const int w       = tid >> 6;
        const int l       = tid & 63;
        const int rowhalf = w >> 2;
        const int cgrp    = w & 3;
        const int lrow    = l & 15;
        const int khalf   = l >> 4;

        const float*  ap0 = input + (base + rowhalf * 16 + lrow) * KF + khalf * 8;
        const __bf16* bp0 = Bt + (cgrp * 64 + lrow) * KF + khalf * 8;

        f32x4 acc0 = {0.f,0.f,0.f,0.f}, acc1 = {0.f,0.f,0.f,0.f};
        f32x4 acc2 = {0.f,0.f,0.f,0.f}, acc3 = {0.f,0.f,0.f,0.f};
#pragma unroll
        for (int ks = 0; ks < 16; ++ks) {
            const int k0 = ks * 32;
            const f32x4 alo = *(const f32x4*)(ap0 + k0);
            const f32x4 ahi = *(const f32x4*)(ap0 + k0 + 4);
            bf16x8 af;
            af[0]=(__bf16)alo[0]; af[1]=(__bf16)alo[1]; af[2]=(__bf16)alo[2]; af[3]=(__bf16)alo[3];
            af[4]=(__bf16)ahi[0]; af[5]=(__bf16)ahi[1]; af[6]=(__bf16)ahi[2]; af[7]=(__bf16)ahi[3];
            const bf16x8 b0 = *(const bf16x8*)(bp0 + 0 * 16 * KF + k0);
            const bf16x8 b1 = *(const bf16x8*)(bp0 + 1 * 16 * KF + k0);
            const bf16x8 b2 = *(const bf16x8*)(bp0 + 2 * 16 * KF + k0);
            const bf16x8 b3 = *(const bf16x8*)(bp0 + 3 * 16 * KF + k0);
            acc0 = __builtin_amdgcn_mfma_f32_16x16x32_bf16(af, b0, acc0, 0, 0, 0);
            acc1 = __builtin_amdgcn_mfma_f32_16x16x32_bf16(af, b1, acc1, 0, 0, 0);
            acc2 = __builtin_amdgcn_mfma_f32_16x16x32_bf16(af, b2, acc2, 0, 0, 0);
            acc3 = __builtin_amdgcn_mfma_f32_16x16x32_bf16(af, b3, acc3, 0, 0, 0);
        }
        const int hr = rowhalf * 16 + khalf * 4;
        const int hc = cgrp * 64 + lrow;
#pragma unroll
        for (int r = 0; r < 4; ++r) {
            H[(hr + r) * 257 + hc +  0] = acc0[r];
            H[(hr + r) * 257 + hc + 16] = acc1[r];
            H[(hr + r) * 257 + hc + 32] = acc2[r];
            H[(hr + r) * 257 + hc + 48] = acc3[r];
        }
    }
    // per-row scalars -> LDS (independent of flag)
    if (tid < 32) {
        aL[tid] = ws[WS_AL + base + tid];
        bL[tid] = ws[WS_BE + base + tid];
        gL[tid] = ws[WS_GA + base + tid];
    }
    __syncthreads();

    // ================= consume U/V =================
    if (tid == 0) {
        while (__hip_atomic_load(flag, __ATOMIC_ACQUIRE, __HIP_MEMORY_SCOPE_AGENT) < 16u)
            __builtin_amdgcn_s_sleep(8);
    }
    __syncthreads();
    if (tid < 256) {
        float s = 0.f;
#pragma unroll
        for (int g = 0; g < 16; ++g) s += ws[WS_UP + g * 256 + tid];
        UL[tid] = s;
    } else {
        const int k2 = tid - 256;
        float s = 0.f;
#pragma unroll
        for (int g = 0; g < 16; ++g) s += ws[WS_VP + g * 256 + k2];
        VL[k2] = s;
    }
    __syncthreads();

    // ================= epilogue =================
    {
        const int c0 = (tid & 63) * 4;
        const int r0 = (tid >> 6) * 4;
#pragma unroll
        for (int i = 0; i < 4; ++i) {
            const int row = r0 + i;
            const float A = aL[row], B = bL[row], G = gL[row];
            const float* hp = &H[row * 257 + c0];
            f32x4 o;
            o[0] = A * UL[c0 + 0] + B * VL[c0 + 0] - G * hp[0];
            o[1] = A * UL[c0 + 1] + B * VL[c0 + 1] - G * hp[1];
            o[2] = A * UL[c0 + 2] + B * VL[c0 + 2] - G * hp[2];
            o[3] = A * UL[c0 + 3] + B * VL[c0 + 3] - G * hp[3];
            *(f32x4*)(out + (base + row) * OF + c0) = o;
        }
    }
}

// ---------------------------------------------------------------------------
extern "C" void kernel_launch(void* const* d_in, const int* in_sizes, int n_in,
                              void* d_out, int out_size, void* d_ws, size_t ws_size,
                              hipStream_t stream) {
    const float* input  = (const float*)d_in[0];
    const float* w_s    = (const float*)d_in[1];
    const float* w_r    = (const float*)d_in[2];
    const float* weight = (const float*)d_in[3];
    float* ws = (float*)d_ws;
    __hip_bfloat16* Bt = (__hip_bfloat16*)((char*)d_ws + BT_BYTE_OFF);
    float* out = (float*)d_out;

    hipLaunchKernelGGL(kA, dim3(256), dim3(512), 0, stream, input, w_s, w_r, weight, ws, Bt);
    hipLaunchKernelGGL(kC, dim3(256), dim3(512), 0, stream, input, Bt, weight, ws, out);
}

// Round 8
// 91.390 us; speedup vs baseline: 1.1782x; 1.1782x over previous
//
#include <hip/hip_runtime.h>
#include <hip/hip_bf16.h>

#define NR 8192
#define KF 512
#define OF 256

// ws float offsets
#define WS_AL   0        // alpha [8192]
#define WS_BE   8192     // beta  [8192]
#define WS_GA   16384    // gamma [8192]
#define WS_PU   24576    // 256 blocks x 256
#define WS_PV   90112    // 256 blocks x 256
#define WS_U    155648   // 256
#define WS_V    155904   // 256
#define HB_BYTE_OFF 624640                  // bf16 H [8192][256] = 4 MB
#define BT_BYTE_OFF (HB_BYTE_OFF + 4194304) // bf16 Bt [256][512] = 256 KB

typedef float f32x4 __attribute__((ext_vector_type(4)));
typedef __bf16 bf16x8 __attribute__((ext_vector_type(8)));

// ---------------------------------------------------------------------------
// kW: weight [512][256] f32 -> Bt [256][512] bf16 (one-time transpose)
// 32 blocks x 256 thr, one 64x64 tile each. Coalesced loads AND stores.
// ---------------------------------------------------------------------------
__global__ __launch_bounds__(256) void kW(const float* __restrict__ weight,
                                          __hip_bfloat16* __restrict__ BtH) {
    __shared__ float tile[64][65];
    const int t   = blockIdx.x;
    const int k0  = (t & 7) * 64;
    const int c0  = (t >> 3) * 64;
    const int tid = threadIdx.x;
    const int cc  = (tid & 15) * 4;
    const int kr0 = tid >> 4;
#pragma unroll
    for (int it = 0; it < 4; ++it) {
        const int kr = it * 16 + kr0;
        const f32x4 v = *(const f32x4*)(weight + (k0 + kr) * OF + c0 + cc);
        tile[kr][cc + 0] = v[0]; tile[kr][cc + 1] = v[1];
        tile[kr][cc + 2] = v[2]; tile[kr][cc + 3] = v[3];
    }
    __syncthreads();
    __bf16* Bt = (__bf16*)BtH;
    const int cr = tid >> 2;
    const int kq = (tid & 3) * 16;
#pragma unroll
    for (int h = 0; h < 2; ++h) {
        bf16x8 v;
#pragma unroll
        for (int j = 0; j < 8; ++j) v[j] = (__bf16)tile[kq + h * 8 + j][cr];
        *(bf16x8*)(Bt + (c0 + cr) * KF + k0 + kq + h * 8) = v;
    }
}

// ---------------------------------------------------------------------------
// k1: 256 blocks x 512 thr, 32 rows each (R5 skeleton, cheap staging):
//  - local Sa/Sb, per-row alpha/beta/gamma -> ws, p/q -> LDS
//  - 4 K-chunks: stage Wt[256][128+pad] bf16 from pre-transposed Bt
//    (8 x 16B coalesced loads + 8 ds_write_b128 per thread), MFMA from LDS
//  - H -> LDS; partial U/V -> ws; H -> bf16 -> global
// ---------------------------------------------------------------------------
__global__ __launch_bounds__(512) void k1(const float* __restrict__ input,
                                          const float* __restrict__ w_s,
                                          const float* __restrict__ w_r,
                                          const __hip_bfloat16* __restrict__ BtH,
                                          float* __restrict__ ws,
                                          __hip_bfloat16* __restrict__ HbH) {
    __shared__ float H[32 * 257];          // 32.9 KB
    __shared__ __bf16 Wt[256][136];        // 69.6 KB (proven pad)
    __shared__ float pl[32], ql[32];
    __shared__ float wred[16];

    const int tid  = threadIdx.x;
    const int blk  = blockIdx.x;
    const int base = blk * 32;
    __bf16* Hb = (__bf16*)HbH;
    const __bf16* Bt = (const __bf16*)BtH;

    // ---- Sa/Sb: full local reduction (vectorized, L2-hot) ----
    float la = 0.f, lb = 0.f;
#pragma unroll
    for (int i = 0; i < 4; ++i) {
        const int off = i * 2048 + tid * 4;
        const f32x4 va = *(const f32x4*)(w_s + off);
        const f32x4 vb = *(const f32x4*)(w_r + off);
        la += fabsf(va[0]) + fabsf(va[1]) + fabsf(va[2]) + fabsf(va[3]);
        lb += fabsf(vb[0]) + fabsf(vb[1]) + fabsf(vb[2]) + fabsf(vb[3]);
    }
#pragma unroll
    for (int o = 32; o > 0; o >>= 1) {
        la += __shfl_down(la, o);
        lb += __shfl_down(lb, o);
    }
    if ((tid & 63) == 0) { wred[tid >> 6] = la; wred[8 + (tid >> 6)] = lb; }
    __syncthreads();

    // ---- per-row scalars ----
    if (tid < 32) {
        float Sa = 0.f, Sb = 0.f;
#pragma unroll
        for (int i = 0; i < 8; ++i) { Sa += wred[i]; Sb += wred[8 + i]; }
        const int row = base + tid;
        const float a = fabsf(w_s[row]);
        const float b = fabsf(w_r[row]);
        float s = 0.5f * (a * (Sb - b) + b * (Sa - a));
        if (s == 0.f) s = 1.f;
        const float d = 1.0f / sqrtf(s);
        ws[WS_AL + row] = 0.5f * d * a;
        ws[WS_BE + row] = 0.5f * d * b;
        ws[WS_GA + row] = d * d * a * b;
        pl[tid] = d * b;
        ql[tid] = d * a;
    }

    // ---- MFMA over 4 K-chunks of 128, B staged LDS<-Bt with 16B loads ----
    const int w       = tid >> 6;
    const int l       = tid & 63;
    const int rowhalf = w >> 2;
    const int cgrp    = w & 3;
    const int lrow    = l & 15;
    const int khalf   = l >> 4;

    const int cST = tid >> 4;         // 0..31 (c within pass)
    const int kST = (tid & 15) * 8;   // k octet within chunk

    f32x4 acc0 = {0.f,0.f,0.f,0.f}, acc1 = {0.f,0.f,0.f,0.f};
    f32x4 acc2 = {0.f,0.f,0.f,0.f}, acc3 = {0.f,0.f,0.f,0.f};

    for (int ch = 0; ch < 4; ++ch) {
        // stage: 8 passes x (one 16B coalesced load from Bt + one b128 LDS write)
#pragma unroll
        for (int p = 0; p < 8; ++p) {
            const int c = p * 32 + cST;
            const bf16x8 v = *(const bf16x8*)(Bt + c * KF + ch * 128 + kST);
            *(bf16x8*)&Wt[c][kST] = v;
        }
        __syncthreads();
#pragma unroll
        for (int kst = 0; kst < 4; ++kst) {
            const int klocal = kst * 32 + khalf * 8;
            const int kglob  = ch * 128 + klocal;
            const float* ap = input + (base + rowhalf * 16 + lrow) * KF + kglob;
            const f32x4 alo = *(const f32x4*)ap;
            const f32x4 ahi = *(const f32x4*)(ap + 4);
            bf16x8 af;
            af[0]=(__bf16)alo[0]; af[1]=(__bf16)alo[1]; af[2]=(__bf16)alo[2]; af[3]=(__bf16)alo[3];
            af[4]=(__bf16)ahi[0]; af[5]=(__bf16)ahi[1]; af[6]=(__bf16)ahi[2]; af[7]=(__bf16)ahi[3];
            const bf16x8 b0 = *(const bf16x8*)&Wt[cgrp * 64 +  0 + lrow][klocal];
            const bf16x8 b1 = *(const bf16x8*)&Wt[cgrp * 64 + 16 + lrow][klocal];
            const bf16x8 b2 = *(const bf16x8*)&Wt[cgrp * 64 + 32 + lrow][klocal];
            const bf16x8 b3 = *(const bf16x8*)&Wt[cgrp * 64 + 48 + lrow][klocal];
            acc0 = __builtin_amdgcn_mfma_f32_16x16x32_bf16(af, b0, acc0, 0, 0, 0);
            acc1 = __builtin_amdgcn_mfma_f32_16x16x32_bf16(af, b1, acc1, 0, 0, 0);
            acc2 = __builtin_amdgcn_mfma_f32_16x16x32_bf16(af, b2, acc2, 0, 0, 0);
            acc3 = __builtin_amdgcn_mfma_f32_16x16x32_bf16(af, b3, acc3, 0, 0, 0);
        }
        __syncthreads();
    }

    // ---- H accs -> LDS ----
    {
        const int hr = rowhalf * 16 + khalf * 4;
        const int hc = cgrp * 64 + lrow;
#pragma unroll
        for (int r = 0; r < 4; ++r) {
            H[(hr + r) * 257 + hc +  0] = acc0[r];
            H[(hr + r) * 257 + hc + 16] = acc1[r];
            H[(hr + r) * 257 + hc + 32] = acc2[r];
            H[(hr + r) * 257 + hc + 48] = acc3[r];
        }
    }
    __syncthreads();

    // ---- partial U/V (f32 H) ----
    {
        const int k = tid & 255;
        const float* pv = (tid < 256) ? pl : ql;
        float u = 0.f;
#pragma unroll 8
        for (int r = 0; r < 32; ++r) u += pv[r] * H[r * 257 + k];
        if (tid < 256) ws[WS_PU + blk * 256 + k] = u;
        else           ws[WS_PV + blk * 256 + k] = u;
    }

    // ---- H -> bf16 -> global (coalesced) ----
    {
        const int row = tid & 31;
        const int c0  = (tid >> 5) * 16;
        const float* hp = &H[row * 257 + c0];
        bf16x8 v0, v1;
#pragma unroll
        for (int j = 0; j < 8; ++j) v0[j] = (__bf16)hp[j];
#pragma unroll
        for (int j = 0; j < 8; ++j) v1[j] = (__bf16)hp[8 + j];
        __bf16* dst = Hb + (base + row) * OF + c0;
        *(bf16x8*)dst       = v0;
        *(bf16x8*)(dst + 8) = v1;
    }
}

// ---------------------------------------------------------------------------
// k2: reduce 256 partials -> U/V. blocks 0..7 = U, 8..15 = V. No atomics.
// ---------------------------------------------------------------------------
__global__ __launch_bounds__(256) void k2(float* __restrict__ ws) {
    const int b    = blockIdx.x;
    const bool isV = b >= 8;
    const int kb   = (b & 7) * 32;
    const int t    = threadIdx.x;
    const int k    = kb + (t >> 3);
    const int p0   = t & 7;
    const float* P = ws + (isV ? WS_PV : WS_PU);
    float s = 0.f;
#pragma unroll 8
    for (int j = p0; j < 256; j += 8) s += P[j * 256 + k];
#pragma unroll
    for (int o = 4; o > 0; o >>= 1) s += __shfl_down(s, o, 8);
    if (p0 == 0) ws[(isV ? WS_V : WS_U) + k] = s;
}

// ---------------------------------------------------------------------------
// k3: epilogue out[i,k] = al*U + be*V - ga*H. 256 blocks x 256 thr, 32 rows.
// f32x4 stores, 8B bf16 loads.
// ---------------------------------------------------------------------------
__global__ __launch_bounds__(256) void k3(const __hip_bfloat16* __restrict__ HbH,
                                          const float* __restrict__ ws,
                                          float* __restrict__ out) {
    __shared__ float aL[32], bL[32], gL[32], UL[256], VL[256];
    const int tid  = threadIdx.x;
    const int base = blockIdx.x * 32;
    UL[tid] = ws[WS_U + tid];
    VL[tid] = ws[WS_V + tid];
    if (tid < 32) {
        aL[tid] = ws[WS_AL + base + tid];
        bL[tid] = ws[WS_BE + base + tid];
        gL[tid] = ws[WS_GA + base + tid];
    }
    __syncthreads();
    const ushort* Hb = (const ushort*)HbH;
    const int c4 = (tid & 63) * 4;
    const int r0 = (tid >> 6) * 8;
    const float u0 = UL[c4], u1 = UL[c4+1], u2 = UL[c4+2], u3 = UL[c4+3];
    const float v0 = VL[c4], v1 = VL[c4+1], v2 = VL[c4+2], v3 = VL[c4+3];
#pragma unroll
    for (int i = 0; i < 8; ++i) {
        const int r = r0 + i;
        const uint2 hv = *(const uint2*)(Hb + (base + r) * OF + c4);
        const float h0 = __uint_as_float(hv.x << 16);
        const float h1 = __uint_as_float(hv.x & 0xffff0000u);
        const float h2 = __uint_as_float(hv.y << 16);
        const float h3 = __uint_as_float(hv.y & 0xffff0000u);
        const float A = aL[r], B = bL[r], G = gL[r];
        f32x4 o;
        o[0] = A * u0 + B * v0 - G * h0;
        o[1] = A * u1 + B * v1 - G * h1;
        o[2] = A * u2 + B * v2 - G * h2;
        o[3] = A * u3 + B * v3 - G * h3;
        *(f32x4*)(out + (base + r) * OF + c4) = o;
    }
}

// ---------------------------------------------------------------------------
extern "C" void kernel_launch(void* const* d_in, const int* in_sizes, int n_in,
                              void* d_out, int out_size, void* d_ws, size_t ws_size,
                              hipStream_t stream) {
    const float* input  = (const float*)d_in[0];
    const float* w_s    = (const float*)d_in[1];
    const float* w_r    = (const float*)d_in[2];
    const float* weight = (const float*)d_in[3];
    float* ws = (float*)d_ws;
    __hip_bfloat16* Hb = (__hip_bfloat16*)((char*)d_ws + HB_BYTE_OFF);
    __hip_bfloat16* Bt = (__hip_bfloat16*)((char*)d_ws + BT_BYTE_OFF);
    float* out = (float*)d_out;

    hipLaunchKernelGGL(kW, dim3(32),  dim3(256), 0, stream, weight, Bt);
    hipLaunchKernelGGL(k1, dim3(256), dim3(512), 0, stream, input, w_s, w_r, Bt, ws, Hb);
    hipLaunchKernelGGL(k2, dim3(16),  dim3(256), 0, stream, ws);
    hipLaunchKernelGGL(k3, dim3(256), dim3(256), 0, stream, Hb, ws, out);
}

// Round 10
// 90.985 us; speedup vs baseline: 1.1834x; 1.0044x over previous
//
#include <hip/hip_runtime.h>
#include <hip/hip_bf16.h>

#define NR 8192
#define KF 512
#define OF 256

// ws float offsets
#define WS_AL   0        // alpha [8192]
#define WS_BE   8192     // beta  [8192]
#define WS_GA   16384    // gamma [8192]
#define WS_PU   24576    // 256 blocks x 256
#define WS_PV   90112    // 256 blocks x 256
#define WS_U    155648   // 256
#define WS_V    155904   // 256
#define HB_BYTE_OFF 624640                  // bf16 H [8192][256] = 4 MB
#define BT_BYTE_OFF (HB_BYTE_OFF + 4194304) // bf16 Bt [256][512] = 256 KB

typedef float f32x4 __attribute__((ext_vector_type(4)));
typedef __bf16 bf16x8 __attribute__((ext_vector_type(8)));

// ---------------------------------------------------------------------------
// kW: weight [512][256] f32 -> Bt [256][512] bf16 (one-time transpose)
// 32 blocks x 256 thr, one 64x64 tile each. Coalesced loads AND stores.
// ---------------------------------------------------------------------------
__global__ __launch_bounds__(256) void kW(const float* __restrict__ weight,
                                          __hip_bfloat16* __restrict__ BtH) {
    __shared__ float tile[64][65];
    const int t   = blockIdx.x;
    const int k0  = (t & 7) * 64;
    const int c0  = (t >> 3) * 64;
    const int tid = threadIdx.x;
    const int cc  = (tid & 15) * 4;
    const int kr0 = tid >> 4;
#pragma unroll
    for (int it = 0; it < 4; ++it) {
        const int kr = it * 16 + kr0;
        const f32x4 v = *(const f32x4*)(weight + (k0 + kr) * OF + c0 + cc);
        tile[kr][cc + 0] = v[0]; tile[kr][cc + 1] = v[1];
        tile[kr][cc + 2] = v[2]; tile[kr][cc + 3] = v[3];
    }
    __syncthreads();
    __bf16* Bt = (__bf16*)BtH;
    const int cr = tid >> 2;
    const int kq = (tid & 3) * 16;
#pragma unroll
    for (int h = 0; h < 2; ++h) {
        bf16x8 v;
#pragma unroll
        for (int j = 0; j < 8; ++j) v[j] = (__bf16)tile[kq + h * 8 + j][cr];
        *(bf16x8*)(Bt + (c0 + cr) * KF + k0 + kq + h * 8) = v;
    }
}

// ---------------------------------------------------------------------------
// k1: 256 blocks x 512 thr, 32 rows each (R8 skeleton + reg-double-buffered
// staging: chunk ch+1's Bt loads issue before chunk ch's MFMA, vmcnt waits
// land at the next ds_write -> L2 latency hidden under compute)
// ---------------------------------------------------------------------------
__global__ __launch_bounds__(512) void k1(const float* __restrict__ input,
                                          const float* __restrict__ w_s,
                                          const float* __restrict__ w_r,
                                          const __hip_bfloat16* __restrict__ BtH,
                                          float* __restrict__ ws,
                                          __hip_bfloat16* __restrict__ HbH) {
    __shared__ float H[32 * 257];          // 32.9 KB
    __shared__ __bf16 Wt[256][136];        // 69.6 KB (proven pad)
    __shared__ float pl[32], ql[32];
    __shared__ float wred[16];

    const int tid  = threadIdx.x;
    const int blk  = blockIdx.x;
    const int base = blk * 32;
    __bf16* Hb = (__bf16*)HbH;
    const __bf16* Bt = (const __bf16*)BtH;

    // ---- Sa/Sb: full local reduction (vectorized, L2-hot) ----
    float la = 0.f, lb = 0.f;
#pragma unroll
    for (int i = 0; i < 4; ++i) {
        const int off = i * 2048 + tid * 4;
        const f32x4 va = *(const f32x4*)(w_s + off);
        const f32x4 vb = *(const f32x4*)(w_r + off);
        la += fabsf(va[0]) + fabsf(va[1]) + fabsf(va[2]) + fabsf(va[3]);
        lb += fabsf(vb[0]) + fabsf(vb[1]) + fabsf(vb[2]) + fabsf(vb[3]);
    }
#pragma unroll
    for (int o = 32; o > 0; o >>= 1) {
        la += __shfl_down(la, o);
        lb += __shfl_down(lb, o);
    }
    if ((tid & 63) == 0) { wred[tid >> 6] = la; wred[8 + (tid >> 6)] = lb; }
    __syncthreads();

    // ---- per-row scalars ----
    if (tid < 32) {
        float Sa = 0.f, Sb = 0.f;
#pragma unroll
        for (int i = 0; i < 8; ++i) { Sa += wred[i]; Sb += wred[8 + i]; }
        const int row = base + tid;
        const float a = fabsf(w_s[row]);
        const float b = fabsf(w_r[row]);
        float s = 0.5f * (a * (Sb - b) + b * (Sa - a));
        if (s == 0.f) s = 1.f;
        const float d = 1.0f / sqrtf(s);
        ws[WS_AL + row] = 0.5f * d * a;
        ws[WS_BE + row] = 0.5f * d * b;
        ws[WS_GA + row] = d * d * a * b;
        pl[tid] = d * b;
        ql[tid] = d * a;
    }

    // ---- MFMA over 4 K-chunks of 128; staging double-buffered in regs ----
    const int w       = tid >> 6;
    const int l       = tid & 63;
    const int rowhalf = w >> 2;
    const int cgrp    = w & 3;
    const int lrow    = l & 15;
    const int khalf   = l >> 4;

    const int cST = tid >> 4;         // 0..31 (c within pass)
    const int kST = (tid & 15) * 8;   // k octet within chunk

    f32x4 acc0 = {0.f,0.f,0.f,0.f}, acc1 = {0.f,0.f,0.f,0.f};
    f32x4 acc2 = {0.f,0.f,0.f,0.f}, acc3 = {0.f,0.f,0.f,0.f};

    bf16x8 brg0, brg1, brg2, brg3, brg4, brg5, brg6, brg7;
    // preload chunk 0
    {
        const __bf16* sp = Bt + cST * KF + kST;
        brg0 = *(const bf16x8*)(sp +   0 * KF);
        brg1 = *(const bf16x8*)(sp +  32 * KF);
        brg2 = *(const bf16x8*)(sp +  64 * KF);
        brg3 = *(const bf16x8*)(sp +  96 * KF);
        brg4 = *(const bf16x8*)(sp + 128 * KF);
        brg5 = *(const bf16x8*)(sp + 160 * KF);
        brg6 = *(const bf16x8*)(sp + 192 * KF);
        brg7 = *(const bf16x8*)(sp + 224 * KF);
    }

    for (int ch = 0; ch < 4; ++ch) {
        __syncthreads();   // previous chunk's Wt readers done
        *(bf16x8*)&Wt[  0 + cST][kST] = brg0;
        *(bf16x8*)&Wt[ 32 + cST][kST] = brg1;
        *(bf16x8*)&Wt[ 64 + cST][kST] = brg2;
        *(bf16x8*)&Wt[ 96 + cST][kST] = brg3;
        *(bf16x8*)&Wt[128 + cST][kST] = brg4;
        *(bf16x8*)&Wt[160 + cST][kST] = brg5;
        *(bf16x8*)&Wt[192 + cST][kST] = brg6;
        *(bf16x8*)&Wt[224 + cST][kST] = brg7;
        __syncthreads();   // Wt visible
        if (ch < 3) {      // issue next chunk's loads; waited at next ds_write
            const __bf16* sp = Bt + cST * KF + (ch + 1) * 128 + kST;
            brg0 = *(const bf16x8*)(sp +   0 * KF);
            brg1 = *(const bf16x8*)(sp +  32 * KF);
            brg2 = *(const bf16x8*)(sp +  64 * KF);
            brg3 = *(const bf16x8*)(sp +  96 * KF);
            brg4 = *(const bf16x8*)(sp + 128 * KF);
            brg5 = *(const bf16x8*)(sp + 160 * KF);
            brg6 = *(const bf16x8*)(sp + 192 * KF);
            brg7 = *(const bf16x8*)(sp + 224 * KF);
        }
#pragma unroll
        for (int kst = 0; kst < 4; ++kst) {
            const int klocal = kst * 32 + khalf * 8;
            const int kglob  = ch * 128 + klocal;
            const float* ap = input + (base + rowhalf * 16 + lrow) * KF + kglob;
            const f32x4 alo = *(const f32x4*)ap;
            const f32x4 ahi = *(const f32x4*)(ap + 4);
            bf16x8 af;
            af[0]=(__bf16)alo[0]; af[1]=(__bf16)alo[1]; af[2]=(__bf16)alo[2]; af[3]=(__bf16)alo[3];
            af[4]=(__bf16)ahi[0]; af[5]=(__bf16)ahi[1]; af[6]=(__bf16)ahi[2]; af[7]=(__bf16)ahi[3];
            const bf16x8 b0 = *(const bf16x8*)&Wt[cgrp * 64 +  0 + lrow][klocal];
            const bf16x8 b1 = *(const bf16x8*)&Wt[cgrp * 64 + 16 + lrow][klocal];
            const bf16x8 b2 = *(const bf16x8*)&Wt[cgrp * 64 + 32 + lrow][klocal];
            const bf16x8 b3 = *(const bf16x8*)&Wt[cgrp * 64 + 48 + lrow][klocal];
            acc0 = __builtin_amdgcn_mfma_f32_16x16x32_bf16(af, b0, acc0, 0, 0, 0);
            acc1 = __builtin_amdgcn_mfma_f32_16x16x32_bf16(af, b1, acc1, 0, 0, 0);
            acc2 = __builtin_amdgcn_mfma_f32_16x16x32_bf16(af, b2, acc2, 0, 0, 0);
            acc3 = __builtin_amdgcn_mfma_f32_16x16x32_bf16(af, b3, acc3, 0, 0, 0);
        }
    }
    __syncthreads();

    // ---- H accs -> LDS ----
    {
        const int hr = rowhalf * 16 + khalf * 4;
        const int hc = cgrp * 64 + lrow;
#pragma unroll
        for (int r = 0; r < 4; ++r) {
            H[(hr + r) * 257 + hc +  0] = acc0[r];
            H[(hr + r) * 257 + hc + 16] = acc1[r];
            H[(hr + r) * 257 + hc + 32] = acc2[r];
            H[(hr + r) * 257 + hc + 48] = acc3[r];
        }
    }
    __syncthreads();

    // ---- partial U/V (f32 H) ----
    {
        const int k = tid & 255;
        const float* pv = (tid < 256) ? pl : ql;
        float u = 0.f;
#pragma unroll 8
        for (int r = 0; r < 32; ++r) u += pv[r] * H[r * 257 + k];
        if (tid < 256) ws[WS_PU + blk * 256 + k] = u;
        else           ws[WS_PV + blk * 256 + k] = u;
    }

    // ---- H -> bf16 -> global (coalesced) ----
    {
        const int row = tid & 31;
        const int c0  = (tid >> 5) * 16;
        const float* hp = &H[row * 257 + c0];
        bf16x8 v0, v1;
#pragma unroll
        for (int j = 0; j < 8; ++j) v0[j] = (__bf16)hp[j];
#pragma unroll
        for (int j = 0; j < 8; ++j) v1[j] = (__bf16)hp[8 + j];
        __bf16* dst = Hb + (base + row) * OF + c0;
        *(bf16x8*)dst       = v0;
        *(bf16x8*)(dst + 8) = v1;
    }
}

// ---------------------------------------------------------------------------
// k2: reduce 256 partials -> U/V. blocks 0..7 = U, 8..15 = V. No atomics.
// ---------------------------------------------------------------------------
__global__ __launch_bounds__(256) void k2(float* __restrict__ ws) {
    const int b    = blockIdx.x;
    const bool isV = b >= 8;
    const int kb   = (b & 7) * 32;
    const int t    = threadIdx.x;
    const int k    = kb + (t >> 3);
    const int p0   = t & 7;
    const float* P = ws + (isV ? WS_PV : WS_PU);
    float s = 0.f;
#pragma unroll 8
    for (int j = p0; j < 256; j += 8) s += P[j * 256 + k];
#pragma unroll
    for (int o = 4; o > 0; o >>= 1) s += __shfl_down(s, o, 8);
    if (p0 == 0) ws[(isV ? WS_V : WS_U) + k] = s;
}

// ---------------------------------------------------------------------------
// k3: epilogue out[i,k] = al*U + be*V - ga*H. 256 blocks x 256 thr, 32 rows.
// f32x4 stores, 8B bf16 loads.
// ---------------------------------------------------------------------------
__global__ __launch_bounds__(256) void k3(const __hip_bfloat16* __restrict__ HbH,
                                          const float* __restrict__ ws,
                                          float* __restrict__ out) {
    __shared__ float aL[32], bL[32], gL[32], UL[256], VL[256];
    const int tid  = threadIdx.x;
    const int base = blockIdx.x * 32;
    UL[tid] = ws[WS_U + tid];
    VL[tid] = ws[WS_V + tid];
    if (tid < 32) {
        aL[tid] = ws[WS_AL + base + tid];
        bL[tid] = ws[WS_BE + base + tid];
        gL[tid] = ws[WS_GA + base + tid];
    }
    __syncthreads();
    const ushort* Hb = (const ushort*)HbH;
    const int c4 = (tid & 63) * 4;
    const int r0 = (tid >> 6) * 8;
    const float u0 = UL[c4], u1 = UL[c4+1], u2 = UL[c4+2], u3 = UL[c4+3];
    const float v0 = VL[c4], v1 = VL[c4+1], v2 = VL[c4+2], v3 = VL[c4+3];
#pragma unroll
    for (int i = 0; i < 8; ++i) {
        const int r = r0 + i;
        const uint2 hv = *(const uint2*)(Hb + (base + r) * OF + c4);
        const float h0 = __uint_as_float(hv.x << 16);
        const float h1 = __uint_as_float(hv.x & 0xffff0000u);
        const float h2 = __uint_as_float(hv.y << 16);
        const float h3 = __uint_as_float(hv.y & 0xffff0000u);
        const float A = aL[r], B = bL[r], G = gL[r];
        f32x4 o;
        o[0] = A * u0 + B * v0 - G * h0;
        o[1] = A * u1 + B * v1 - G * h1;
        o[2] = A * u2 + B * v2 - G * h2;
        o[3] = A * u3 + B * v3 - G * h3;
        *(f32x4*)(out + (base + r) * OF + c4) = o;
    }
}

// ---------------------------------------------------------------------------
extern "C" void kernel_launch(void* const* d_in, const int* in_sizes, int n_in,
                              void* d_out, int out_size, void* d_ws, size_t ws_size,
                              hipStream_t stream) {
    const float* input  = (const float*)d_in[0];
    const float* w_s    = (const float*)d_in[1];
    const float* w_r    = (const float*)d_in[2];
    const float* weight = (const float*)d_in[3];
    float* ws = (float*)d_ws;
    __hip_bfloat16* Hb = (__hip_bfloat16*)((char*)d_ws + HB_BYTE_OFF);
    __hip_bfloat16* Bt = (__hip_bfloat16*)((char*)d_ws + BT_BYTE_OFF);
    float* out = (float*)d_out;

    hipLaunchKernelGGL(kW, dim3(32),  dim3(256), 0, stream, weight, Bt);
    hipLaunchKernelGGL(k1, dim3(256), dim3(512), 0, stream, input, w_s, w_r, Bt, ws, Hb);
    hipLaunchKernelGGL(k2, dim3(16),  dim3(256), 0, stream, ws);
    hipLaunchKernelGGL(k3, dim3(256), dim3(256), 0, stream, Hb, ws, out);
}